// Round 16
// baseline (890.426 us; speedup 1.0000x reference)
//
#include <hip/hip_runtime.h>

#define HIDDEN 448

typedef __attribute__((ext_vector_type(8))) short short8;
typedef __attribute__((ext_vector_type(4))) float f32x4;

// ---------- bf16 helpers ----------
__device__ __forceinline__ unsigned short f2bf(float f) {
    unsigned int u = __float_as_uint(f);
    u = (u + 0x7fffu + ((u >> 16) & 1u)) >> 16;   // RTNE
    return (unsigned short)u;
}
__device__ __forceinline__ float bf2f(unsigned short h) {
    return __uint_as_float(((unsigned int)h) << 16);
}
__device__ __forceinline__ unsigned int cvt_pk_bf16(float a, float b) {
    unsigned int r;
    asm("v_cvt_pk_bf16_f32 %0, %1, %2" : "=v"(r) : "v"(a), "v"(b));
    return r;
}
// async global->LDS, 16B per lane (wave-uniform LDS base + lane*16)
__device__ __forceinline__ void async16(void* lds, const void* g) {
    __builtin_amdgcn_global_load_lds(
        (const __attribute__((address_space(1))) unsigned int*)g,
        (__attribute__((address_space(3))) unsigned int*)lds, 16, 0, 0);
}

// chunk swizzle f(row) = (row>>1)&3 on 8-elem chunks within each 32-elem half
// ================= fused prep kernel (all outputs chunk-swizzled) ==========
__global__ __launch_bounds__(256) void prep_all_kernel(
    const float* __restrict__ W_i, const float* __restrict__ W_h,
    const float* __restrict__ W_o,
    const float* __restrict__ fbonds, const float* __restrict__ fatoms,
    unsigned short* __restrict__ WhcatT, unsigned short* __restrict__ WocatT,
    unsigned short* __restrict__ fbondsP, unsigned short* __restrict__ fatomsP,
    int n_bonds, int n_atoms, int eFb, int eFa)
{
    const int eww = 448 * 512;
    int idx = blockIdx.x * 256 + threadIdx.x;
    if (idx < 2 * eww) {
        // weight concat: seg 0 -> [W_i | W_h], seg 1 -> [W_o_top | W_o_bot]
        const int seg = idx >= eww;
        const int i = seg ? idx - eww : idx;
        const int n = i >> 9, k = i & 511;
        const float* Wtop = seg ? W_o : W_i;
        const float* Wbot = seg ? (W_o + 38 * HIDDEN) : W_h;
        const int Ktop = seg ? 38 : 49;
        float v = 0.0f;
        if (k < Ktop) v = Wtop[k * HIDDEN + n];
        else if (k >= 64) v = Wbot[(k - 64) * HIDDEN + n];
        unsigned short* out = seg ? WocatT : WhcatT;
        out[(size_t)n * 512 + (k ^ (((n >> 1) & 3) << 3))] = f2bf(v);
        return;
    }
    idx -= 2 * eww;
    if (idx < eFb) {
        const int row = idx >> 6, k = idx & 63;
        const float v = (row < n_bonds && k < 49) ? fbonds[(size_t)row * 49 + k] : 0.0f;
        fbondsP[(size_t)row * 64 + (k ^ (((row >> 1) & 3) << 3))] = f2bf(v);
        return;
    }
    idx -= eFb;
    if (idx < eFa) {
        const int row = idx >> 6, k = idx & 63;
        const float v = (row < n_atoms && k < 38) ? fatoms[(size_t)row * 38 + k] : 0.0f;
        fatomsP[(size_t)row * 64 + (k ^ (((row >> 1) & 3) << 3))] = f2bf(v);
    }
}

// ================= fused gather+MFMA GEMM (As double-buffered) =============
// GRAPH=0: out = relu(Apad @ BT^T)              (nsteps=2)
// GRAPH=1: A = [Apad | gathersum6(Xq,graph)]    (nsteps=16)
// Pair q (steps 2q,2q+1) reads As[q&1]; dequant of pair q+1 runs in the MFMA
// shadow of step 2q, committing to As[(q+1)&1]; pf loads issue at odd steps.
// OUTQ=1: q8 out + per-row scale (LDS-overlay epilogue).
// OUTQ=0: per-molecule atomic-sum into dout (rows mol-sorted, run-reduced).
template<int GRAPH, int OUTQ>
__global__ __launch_bounds__(512, 4) void gemm_mfma_kernel(
    const unsigned short* __restrict__ Apad,
    const unsigned char* __restrict__ Xq,
    const float* __restrict__ Xs,
    const int* __restrict__ graph,
    const unsigned short* __restrict__ BT,
    const float* __restrict__ bias,
    unsigned char* __restrict__ outq,
    float* __restrict__ outs,
    const int* __restrict__ molv,
    float* __restrict__ dout,
    int M, int nsteps)
{
    __shared__ __align__(16) unsigned char smem[46080];
    // As[0]@0 (8KB), As[1]@8192, Bs@16384 (28KB), rmax@45056 (1KB)
    unsigned short* Bs = (unsigned short*)(smem + 16384);  // [448][32] linear
    float* rmaxbuf = (float*)(smem + 45056);               // [64][4]

    const int tid = threadIdx.x, lane = tid & 63, wv = tid >> 6;
    const int row0 = blockIdx.x * 64;
    const int wrow = (wv & 1) * 32;        // M-half of this wave
    const int wcol = (wv >> 1) * 112;      // N-quarter of this wave
    const int rr = lane & 15, ch = lane >> 4;
    const int lrow = lane >> 2, lq = lane & 3;   // gload_lds decomposition

    // fused-gather: thread owns one 16B chunk (8 elems) of row tid>>3
    const int arow = tid >> 3, asub = tid & 7;
    const int ahh = asub >> 2, ac = asub & 3;    // 32-half, chunk in half
    const int awaddr = arow * 64 + ahh * 32 + ((ac ^ ((arow >> 1) & 3)) << 3);

    int goff[6]; float gscl[6]; uint2 pf[6];
    if (GRAPH) {
        const int grow = row0 + arow;
        const bool ok = grow < M;
        #pragma unroll
        for (int j = 0; j < 6; ++j) {
            const int gj = ok ? graph[(size_t)grow * 6 + j] : 0;
            goff[j] = gj * 448;
            gscl[j] = ok ? Xs[gj] : 0.0f;
        }
        #pragma unroll
        for (int j = 0; j < 6; ++j)   // pre-loop pf: bytes [0,64) = pair 1
            pf[j] = *(const uint2*)(Xq + goff[j] + asub * 8);
    }

    f32x4 acc[2][7] = {};

    for (int s = 0; s < nsteps; ++s) {
        const int q = s >> 1;   // current pair
        // ---- region 1: async staging
        #pragma unroll
        for (int i = 0; i < 4; ++i) {
            const int t = wv + 8 * i;
            if (t < 28)
                async16(Bs + t * 512 + lane * 8,
                        BT + (size_t)(t * 16 + lrow) * 512 + s * 32 + lq * 8);
        }
        if (s == 0)   // whole [64][64] Apad tile -> As[0], 8 x 1KB chunks
            async16((unsigned short*)smem + wv * 512 + lane * 8,
                    Apad + (size_t)(row0 + wv * 8) * 64 + lane * 8);
        __syncthreads();

        // ---- region 2 ----
        // odd steps: issue pf for pair q+2 (bytes (q+1)*64), consumed next step
        if (GRAPH && (s & 1) && s <= 11) {
            const int pb = (q + 1) * 64;
            #pragma unroll
            for (int j = 0; j < 6; ++j)
                pf[j] = *(const uint2*)(Xq + goff[j] + pb + asub * 8);
        }

        // ds_read current fragments from As[q&1]
        unsigned short* AsCur = (unsigned short*)(smem + (size_t)(q & 1) * 8192);
        const int hoff = (s & 1) * 32;
        short8 av[2], bv[7];
        #pragma unroll
        for (int m = 0; m < 2; ++m) {
            const int r = wrow + m * 16 + rr;
            av[m] = *(const short8*)&AsCur[r * 64 + hoff + ((ch ^ ((r >> 1) & 3)) << 3)];
        }
        #pragma unroll
        for (int n = 0; n < 7; ++n) {
            const int cl = wcol + n * 16 + rr;
            bv[n] = *(const short8*)&Bs[cl * 32 + ((ch ^ ((cl >> 1) & 3)) << 3)];
        }
        // MFMA
        #pragma unroll
        for (int n = 0; n < 7; ++n)
            #pragma unroll
            for (int m = 0; m < 2; ++m)
                acc[m][n] = __builtin_amdgcn_mfma_f32_16x16x32_bf16(
                    av[m], bv[n], acc[m][n], 0, 0, 0);

        // even steps: dequant pair q+1 -> As[(q+1)&1] (overlaps MFMA pipe;
        // pf regs were drained at the previous barrier -> pure VALU here)
        if (GRAPH && !(s & 1) && s <= 12) {
            float a0 = 0, a1 = 0, a2 = 0, a3 = 0, a4 = 0, a5 = 0, a6 = 0, a7 = 0;
            #pragma unroll
            for (int j = 0; j < 6; ++j) {
                const uint2 b = pf[j];
                const float sc = gscl[j];
                a0 += (float)(b.x & 255u) * sc;
                a1 += (float)((b.x >> 8) & 255u) * sc;
                a2 += (float)((b.x >> 16) & 255u) * sc;
                a3 += (float)(b.x >> 24) * sc;
                a4 += (float)(b.y & 255u) * sc;
                a5 += (float)((b.y >> 8) & 255u) * sc;
                a6 += (float)((b.y >> 16) & 255u) * sc;
                a7 += (float)(b.y >> 24) * sc;
            }
            uint4 w;
            w.x = cvt_pk_bf16(a0, a1);
            w.y = cvt_pk_bf16(a2, a3);
            w.z = cvt_pk_bf16(a4, a5);
            w.w = cvt_pk_bf16(a6, a7);
            unsigned short* AsNxt =
                (unsigned short*)(smem + (size_t)((q + 1) & 1) * 8192);
            *(uint4*)&AsNxt[awaddr] = w;
        }

        __syncthreads();
    }

    const int r4 = ch << 2;

    if (OUTQ) {
        // per-lane row max over this wave's 7 n-cols (relu clamps at 0)
        float rpm[2][4];
        #pragma unroll
        for (int m = 0; m < 2; ++m)
            #pragma unroll
            for (int j = 0; j < 4; ++j) {
                float mx = 0.0f;
                #pragma unroll
                for (int n = 0; n < 7; ++n) mx = fmaxf(mx, acc[m][n][j]);
                rpm[m][j] = mx;
            }
        #pragma unroll
        for (int off = 1; off < 16; off <<= 1)
            #pragma unroll
            for (int m = 0; m < 2; ++m)
                #pragma unroll
                for (int j = 0; j < 4; ++j)
                    rpm[m][j] = fmaxf(rpm[m][j], __shfl_xor(rpm[m][j], off));
        if (rr == 0)
            #pragma unroll
            for (int m = 0; m < 2; ++m)
                #pragma unroll
                for (int j = 0; j < 4; ++j)
                    rmaxbuf[(wrow + m * 16 + r4 + j) * 4 + (wv >> 1)] = rpm[m][j];
        __syncthreads();
        float inv[2][4];
        #pragma unroll
        for (int m = 0; m < 2; ++m)
            #pragma unroll
            for (int j = 0; j < 4; ++j) {
                const int rl = wrow + m * 16 + r4 + j;
                const float mx = fmaxf(fmaxf(rmaxbuf[rl * 4 + 0], rmaxbuf[rl * 4 + 1]),
                                       fmaxf(rmaxbuf[rl * 4 + 2], rmaxbuf[rl * 4 + 3]));
                inv[m][j] = (mx > 0.0f) ? (255.0f / mx) : 0.0f;
                if (wv < 2 && rr == 0 && row0 + rl < M)
                    outs[row0 + rl] = mx * (1.0f / 255.0f);
            }
        __syncthreads();   // rmax reads done before q8 overlays staging LDS
        unsigned char* q8 = smem;   // [64][448] overlay (28KB < rmax offset)
        #pragma unroll
        for (int m = 0; m < 2; ++m)
            #pragma unroll
            for (int j = 0; j < 4; ++j) {
                const int rl = wrow + m * 16 + r4 + j;
                #pragma unroll
                for (int n = 0; n < 7; ++n) {
                    const float v = fmaxf(acc[m][n][j], 0.0f);
                    q8[rl * 448 + wcol + n * 16 + rr] =
                        (unsigned char)__float2uint_rn(fminf(v * inv[m][j], 255.0f));
                }
            }
        __syncthreads();
        // coalesced copy-out: 1792 x uint4
        #pragma unroll
        for (int i = 0; i < 4; ++i) {
            const int u = tid + 512 * i;
            if (u < 1792 && row0 + u / 28 < M)
                ((uint4*)(outq + (size_t)row0 * 448))[u] = ((const uint4*)q8)[u];
        }
    } else {
        // fused per-molecule sum: rows are mol-sorted -> run-length reduce
        int mols[2][4];
        #pragma unroll
        for (int m = 0; m < 2; ++m)
            #pragma unroll
            for (int j = 0; j < 4; ++j) {
                const int row = row0 + wrow + m * 16 + r4 + j;
                mols[m][j] = (row < M) ? molv[row] : -1;
            }
        #pragma unroll
        for (int n = 0; n < 7; ++n) {
            const int col = wcol + n * 16 + rr;
            const float bsv = bias ? bias[col] : 0.0f;
            #pragma unroll
            for (int m = 0; m < 2; ++m) {
                int curmol = -1;
                float rs = 0.0f;
                #pragma unroll
                for (int j = 0; j < 4; ++j) {
                    if (mols[m][j] >= 0) {
                        const float v = fmaxf(acc[m][n][j] + bsv, 0.0f);
                        if (mols[m][j] != curmol) {
                            if (curmol >= 0)
                                atomicAdd(dout + (size_t)curmol * HIDDEN + col, rs);
                            curmol = mols[m][j];
                            rs = v;
                        } else {
                            rs += v;
                        }
                    }
                }
                if (curmol >= 0)
                    atomicAdd(dout + (size_t)curmol * HIDDEN + col, rs);
            }
        }
    }
}

// ================= tail kernels =================
// out[m][c] /= count(m)   (counts via binary search on sorted mol_idx)
__global__ void norm_kernel(float* __restrict__ out,
                            const int* __restrict__ mol_idx, int n_atoms)
{
    const int m = blockIdx.x;
    const int c = threadIdx.x;
    int l = 0, r = n_atoms;
    while (l < r) { const int mid = (l + r) >> 1; if (mol_idx[mid] < m) l = mid + 1; else r = mid; }
    const int start = l;
    r = n_atoms;
    while (l < r) { const int mid = (l + r) >> 1; if (mol_idx[mid] < m + 1) l = mid + 1; else r = mid; }
    out[(size_t)m * HIDDEN + c] /= fmaxf((float)(l - start), 1.0f);
}

__global__ __launch_bounds__(256) void fill_kernel(float* __restrict__ out, int n, float val)
{
    const int i = blockIdx.x * 256 + threadIdx.x;
    if (i < n) out[i] = val;
}

// ================= launch =================
extern "C" void kernel_launch(void* const* d_in, const int* in_sizes, int n_in,
                              void* d_out, int out_size, void* d_ws, size_t ws_size,
                              hipStream_t stream)
{
    const float* fatoms = (const float*)d_in[0];
    const float* fbonds = (const float*)d_in[1];
    const float* W_i    = (const float*)d_in[2];
    const float* W_h    = (const float*)d_in[3];
    const float* W_o    = (const float*)d_in[4];
    const float* b_o    = (const float*)d_in[5];
    const int*   agraph = (const int*)d_in[6];
    const int*   bgraph = (const int*)d_in[7];
    const int*   mol_idx= (const int*)d_in[8];

    const int n_atoms = in_sizes[0] / 38;          // 80000
    const int n_bonds = in_sizes[1] / 49;          // 160001
    const int n_mols  = out_size / HIDDEN;         // 4000

    const int Mb_b = (n_bonds + 63) & ~63;         // 160064
    const int Mb_a = (n_atoms + 63) & ~63;         // 80000

    const size_t eW  = (size_t)448 * 512;
    const size_t eFb = (size_t)Mb_b * 64;
    const size_t eFa = (size_t)Mb_a * 64;
    const size_t eX  = (size_t)Mb_b * 448;         // q8 bytes per buffer

    // bytes (~176 MB; ws = 256 MiB)
    const size_t need = 2 * eW * 2 + eFb * 2 + eFa * 2 +
                        2 * eX + 2 * (size_t)Mb_b * 4;

    const dim3 blk(256);

    if (ws_size >= need) {
        unsigned short* WhcatT  = (unsigned short*)d_ws;
        unsigned short* WocatT  = WhcatT + eW;
        unsigned short* fbondsP = WocatT + eW;
        unsigned short* fatomsP = fbondsP + eFb;
        unsigned char*  Xq0     = (unsigned char*)(fatomsP + eFa);
        unsigned char*  Xq1     = Xq0 + eX;
        float*          Xs0     = (float*)(Xq1 + eX);
        float*          Xs1     = Xs0 + Mb_b;

        // zero the accumulation target
        hipMemsetAsync(d_out, 0, (size_t)out_size * sizeof(float), stream);

        // fused prep: weights + padded features, one launch
        const int prep_total = 2 * (int)eW + (int)eFb + (int)eFa;
        hipLaunchKernelGGL(prep_all_kernel, dim3((prep_total + 255) / 256), blk, 0, stream,
                           W_i, W_h, W_o, fbonds, fatoms,
                           WhcatT, WocatT, fbondsP, fatomsP,
                           n_bonds, n_atoms, (int)eFb, (int)eFa);

        const dim3 gB(Mb_b / 64), gA(Mb_a / 64), tpb(512);

        unsigned char* Xq[2] = {Xq0, Xq1};
        float*         Xs[2] = {Xs0, Xs1};

        // X[0] = q8(relu(fbonds @ W_i))
        hipLaunchKernelGGL((gemm_mfma_kernel<0, 1>), gB, tpb, 0, stream,
                           fbondsP, (const unsigned char*)nullptr, (const float*)nullptr,
                           (const int*)nullptr, WhcatT, (const float*)nullptr,
                           Xq[0], Xs[0], (const int*)nullptr, (float*)nullptr,
                           n_bonds, 2);
        // 4 iterations, ping-pong: X[p^1] = q8(relu(fbonds@W_i + gather6(X[p])@W_h))
        int p = 0;
        for (int it = 0; it < 4; ++it) {
            hipLaunchKernelGGL((gemm_mfma_kernel<1, 1>), gB, tpb, 0, stream,
                               fbondsP, Xq[p], Xs[p], bgraph, WhcatT,
                               (const float*)nullptr,
                               Xq[p ^ 1], Xs[p ^ 1], (const int*)nullptr,
                               (float*)nullptr, n_bonds, 16);
            p ^= 1;
        }
        // atom readout fused with molecule-sum:
        // d_out += per-mol sums of relu([fatoms | gather6(X[p])] @ W_o + b_o)
        hipLaunchKernelGGL((gemm_mfma_kernel<1, 0>), gA, tpb, 0, stream,
                           fatomsP, Xq[p], Xs[p], agraph, WocatT, b_o,
                           (unsigned char*)nullptr, (float*)nullptr,
                           mol_idx, (float*)d_out, n_atoms, 16);
        // divide by per-molecule counts
        hipLaunchKernelGGL(norm_kernel, dim3(n_mols), dim3(HIDDEN), 0, stream,
                           (float*)d_out, mol_idx, n_atoms);
    } else {
        // diagnostic: absmax = 2272 + ws_MiB
        const float val = -(float)((double)ws_size / (1024.0 * 1024.0));
        hipLaunchKernelGGL(fill_kernel, dim3((out_size + 255) / 256), blk, 0, stream,
                           (float*)d_out, out_size, val);
    }
}

// Round 17
// 880.706 us; speedup vs baseline: 1.0110x; 1.0110x over previous
//
#include <hip/hip_runtime.h>

#define HIDDEN 448

typedef __attribute__((ext_vector_type(8))) short short8;
typedef __attribute__((ext_vector_type(4))) float f32x4;

// ---------- bf16 helpers ----------
__device__ __forceinline__ unsigned short f2bf(float f) {
    unsigned int u = __float_as_uint(f);
    u = (u + 0x7fffu + ((u >> 16) & 1u)) >> 16;   // RTNE
    return (unsigned short)u;
}
__device__ __forceinline__ float bf2f(unsigned short h) {
    return __uint_as_float(((unsigned int)h) << 16);
}
__device__ __forceinline__ unsigned int cvt_pk_bf16(float a, float b) {
    unsigned int r;
    asm("v_cvt_pk_bf16_f32 %0, %1, %2" : "=v"(r) : "v"(a), "v"(b));
    return r;
}
// async global->LDS, 16B per lane (wave-uniform LDS base + lane*16)
__device__ __forceinline__ void async16(void* lds, const void* g) {
    __builtin_amdgcn_global_load_lds(
        (const __attribute__((address_space(1))) unsigned int*)g,
        (__attribute__((address_space(3))) unsigned int*)lds, 16, 0, 0);
}

// chunk swizzle f(row) = (row>>1)&3 on 8-elem chunks within each 32-elem half
// ================= prep kernels (outputs chunk-swizzled) =================
__global__ __launch_bounds__(256) void prep_wcat_kernel(
    const float* __restrict__ Wtop, int Ktop, const float* __restrict__ Wbot,
    unsigned short* __restrict__ out)
{
    const int idx = blockIdx.x * 256 + threadIdx.x;
    if (idx >= 448 * 512) return;
    const int n = idx >> 9, k = idx & 511;
    float v = 0.0f;
    if (k < Ktop) v = Wtop[k * HIDDEN + n];
    else if (k >= 64) v = Wbot[(k - 64) * HIDDEN + n];
    out[(size_t)n * 512 + (k ^ (((n >> 1) & 3) << 3))] = f2bf(v);
}

// Apad plane-split: out[half][Mb][32]  (half = k>>5; 64-B LDS stride match)
__global__ __launch_bounds__(256) void prep_apad_kernel(
    const float* __restrict__ A, int K, unsigned short* __restrict__ out,
    int Mreal, int total)
{
    const int idx = blockIdx.x * 256 + threadIdx.x;
    if (idx >= total) return;
    const int row = idx >> 6, k = idx & 63;
    const int plane = total >> 1;   // Mb*32 elems per k-half plane
    const float v = (row < Mreal && k < K) ? A[(size_t)row * K + k] : 0.0f;
    const int kk = k & 31;
    out[(size_t)(k >> 5) * plane + (size_t)row * 32
        + (kk ^ (((row >> 1) & 3) << 3))] = f2bf(v);
}

// ================= fused gather+MFMA GEMM (r15-proven schedule) ===========
// GRAPH=0: out = relu(Apad @ BT^T)              (nsteps=2)
// GRAPH=1: A = [Apad | gathersum6(Xq,graph)]    (nsteps=16)
// As = two 4-KB k-half planes (64-B row stride, conflict-floor reads/writes).
// OUTQ=1: q8 out + per-row scale (LDS-overlay epilogue).
// OUTQ=0: per-molecule atomic-sum into dout (rows mol-sorted, run-reduced).
template<int GRAPH, int OUTQ>
__global__ __launch_bounds__(512, 4) void gemm_mfma_kernel(
    const unsigned short* __restrict__ Apad,
    const unsigned char* __restrict__ Xq,
    const float* __restrict__ Xs,
    const int* __restrict__ graph,
    const unsigned short* __restrict__ BT,
    const float* __restrict__ bias,
    unsigned char* __restrict__ outq,
    float* __restrict__ outs,
    const int* __restrict__ molv,
    float* __restrict__ dout,
    int M, int nsteps)
{
    __shared__ __align__(16) unsigned char smem[37888];
    // As plane0 @0 (4KB), plane1 @4096; Bs @8192 (28KB); rmax @36864
    unsigned short* AsF = (unsigned short*)smem;           // flat, planes contiguous
    unsigned short* Bs = (unsigned short*)(smem + 8192);   // [448][32] linear
    float* rmaxbuf = (float*)(smem + 36864);               // [64][4]

    const int tid = threadIdx.x, lane = tid & 63, wv = tid >> 6;
    const int row0 = blockIdx.x * 64;
    const int wrow = (wv & 1) * 32;        // M-half of this wave
    const int wcol = (wv >> 1) * 112;      // N-quarter of this wave
    const int rr = lane & 15, ch = lane >> 4;
    const int lrow = lane >> 2, lq = lane & 3;   // gload_lds decomposition

    // fused-gather: thread owns one 16B chunk (8 elems) of row tid>>3
    const int arow = tid >> 3, asub = tid & 7;
    const int ahh = asub >> 2, ac = asub & 3;    // k-half plane, chunk in half
    // flat elem offset: plane*2048 + row*32 + swizzled chunk
    const int aw = ahh * 2048 + arow * 32 + ((ac ^ ((arow >> 1) & 3)) << 3);

    int goff[6]; float gscl[6]; uint2 pf[6];
    if (GRAPH) {
        const int grow = row0 + arow;
        const bool ok = grow < M;
        #pragma unroll
        for (int j = 0; j < 6; ++j) {
            const int gj = ok ? graph[(size_t)grow * 6 + j] : 0;
            goff[j] = gj * 448;
            gscl[j] = ok ? Xs[gj] : 0.0f;
        }
    }

    f32x4 acc[2][7] = {};

    for (int s = 0; s < nsteps; ++s) {
        // ---- region 1: dequant-commit (even steps) + async staging
        if (GRAPH && s >= 2 && !(s & 1)) {
            // dequant pf (loaded at step s-2) -> whole As tile for steps s,s+1
            float a0 = 0, a1 = 0, a2 = 0, a3 = 0, a4 = 0, a5 = 0, a6 = 0, a7 = 0;
            #pragma unroll
            for (int j = 0; j < 6; ++j) {
                const uint2 b = pf[j];
                const float sc = gscl[j];
                a0 += (float)(b.x & 255u) * sc;
                a1 += (float)((b.x >> 8) & 255u) * sc;
                a2 += (float)((b.x >> 16) & 255u) * sc;
                a3 += (float)(b.x >> 24) * sc;
                a4 += (float)(b.y & 255u) * sc;
                a5 += (float)((b.y >> 8) & 255u) * sc;
                a6 += (float)((b.y >> 16) & 255u) * sc;
                a7 += (float)(b.y >> 24) * sc;
            }
            uint4 w;
            w.x = cvt_pk_bf16(a0, a1);
            w.y = cvt_pk_bf16(a2, a3);
            w.z = cvt_pk_bf16(a4, a5);
            w.w = cvt_pk_bf16(a6, a7);
            *(uint4*)&AsF[aw] = w;
        }
        // B staging for current step
        #pragma unroll
        for (int i = 0; i < 4; ++i) {
            const int t = wv + 8 * i;
            if (t < 28)
                async16(Bs + t * 512 + lane * 8,
                        BT + (size_t)(t * 16 + lrow) * 512 + s * 32 + lq * 8);
        }
        if (s == 0) {
            // Apad tile: 8 x 1KB linear LDS chunks; global is plane-split
            const size_t plane = (size_t)gridDim.x * 2048;   // Mb*32 elems
            async16(AsF + wv * 512 + lane * 8,
                    Apad + (wv >= 4 ? plane : 0)
                         + (size_t)(row0 + (wv & 3) * 16) * 32 + lane * 8);
        }
        __syncthreads();

        // ---- region 2: issue pf for the pair consumed at step s+2
        //      (latency covered by the ds_reads + MFMA below)
        if (GRAPH && !(s & 1) && s <= 12) {
            const int pb = (s >> 1) * 64;
            #pragma unroll
            for (int j = 0; j < 6; ++j)
                pf[j] = *(const uint2*)(Xq + goff[j] + pb + asub * 8);
        }

        // ds_read current fragments (As plane = s&1, 64-B stride)
        const unsigned short* Ash = AsF + (s & 1) * 2048;
        short8 av[2], bv[7];
        #pragma unroll
        for (int m = 0; m < 2; ++m) {
            const int r = wrow + m * 16 + rr;
            av[m] = *(const short8*)&Ash[r * 32 + ((ch ^ ((r >> 1) & 3)) << 3)];
        }
        #pragma unroll
        for (int n = 0; n < 7; ++n) {
            const int cl = wcol + n * 16 + rr;
            bv[n] = *(const short8*)&Bs[cl * 32 + ((ch ^ ((cl >> 1) & 3)) << 3)];
        }
        // MFMA
        #pragma unroll
        for (int n = 0; n < 7; ++n)
            #pragma unroll
            for (int m = 0; m < 2; ++m)
                acc[m][n] = __builtin_amdgcn_mfma_f32_16x16x32_bf16(
                    av[m], bv[n], acc[m][n], 0, 0, 0);

        __syncthreads();
    }

    const int r4 = ch << 2;

    if (OUTQ) {
        // per-lane row max over this wave's 7 n-cols (relu clamps at 0)
        float rpm[2][4];
        #pragma unroll
        for (int m = 0; m < 2; ++m)
            #pragma unroll
            for (int j = 0; j < 4; ++j) {
                float mx = 0.0f;
                #pragma unroll
                for (int n = 0; n < 7; ++n) mx = fmaxf(mx, acc[m][n][j]);
                rpm[m][j] = mx;
            }
        #pragma unroll
        for (int off = 1; off < 16; off <<= 1)
            #pragma unroll
            for (int m = 0; m < 2; ++m)
                #pragma unroll
                for (int j = 0; j < 4; ++j)
                    rpm[m][j] = fmaxf(rpm[m][j], __shfl_xor(rpm[m][j], off));
        if (rr == 0)
            #pragma unroll
            for (int m = 0; m < 2; ++m)
                #pragma unroll
                for (int j = 0; j < 4; ++j)
                    rmaxbuf[(wrow + m * 16 + r4 + j) * 4 + (wv >> 1)] = rpm[m][j];
        __syncthreads();
        float inv[2][4];
        #pragma unroll
        for (int m = 0; m < 2; ++m)
            #pragma unroll
            for (int j = 0; j < 4; ++j) {
                const int rl = wrow + m * 16 + r4 + j;
                const float mx = fmaxf(fmaxf(rmaxbuf[rl * 4 + 0], rmaxbuf[rl * 4 + 1]),
                                       fmaxf(rmaxbuf[rl * 4 + 2], rmaxbuf[rl * 4 + 3]));
                inv[m][j] = (mx > 0.0f) ? (255.0f / mx) : 0.0f;
                if (wv < 2 && rr == 0 && row0 + rl < M)
                    outs[row0 + rl] = mx * (1.0f / 255.0f);
            }
        __syncthreads();   // rmax reads done before q8 overlays staging LDS
        unsigned char* q8 = smem;   // [64][448] overlay (28KB < rmax offset)
        #pragma unroll
        for (int m = 0; m < 2; ++m)
            #pragma unroll
            for (int j = 0; j < 4; ++j) {
                const int rl = wrow + m * 16 + r4 + j;
                #pragma unroll
                for (int n = 0; n < 7; ++n) {
                    const float v = fmaxf(acc[m][n][j], 0.0f);
                    q8[rl * 448 + wcol + n * 16 + rr] =
                        (unsigned char)__float2uint_rn(fminf(v * inv[m][j], 255.0f));
                }
            }
        __syncthreads();
        // coalesced copy-out: 1792 x uint4
        #pragma unroll
        for (int i = 0; i < 4; ++i) {
            const int u = tid + 512 * i;
            if (u < 1792 && row0 + u / 28 < M)
                ((uint4*)(outq + (size_t)row0 * 448))[u] = ((const uint4*)q8)[u];
        }
    } else {
        // fused per-molecule sum: rows are mol-sorted -> run-length reduce
        int mols[2][4];
        #pragma unroll
        for (int m = 0; m < 2; ++m)
            #pragma unroll
            for (int j = 0; j < 4; ++j) {
                const int row = row0 + wrow + m * 16 + r4 + j;
                mols[m][j] = (row < M) ? molv[row] : -1;
            }
        #pragma unroll
        for (int n = 0; n < 7; ++n) {
            const int col = wcol + n * 16 + rr;
            const float bsv = bias ? bias[col] : 0.0f;
            #pragma unroll
            for (int m = 0; m < 2; ++m) {
                int curmol = -1;
                float rs = 0.0f;
                #pragma unroll
                for (int j = 0; j < 4; ++j) {
                    if (mols[m][j] >= 0) {
                        const float v = fmaxf(acc[m][n][j] + bsv, 0.0f);
                        if (mols[m][j] != curmol) {
                            if (curmol >= 0)
                                atomicAdd(dout + (size_t)curmol * HIDDEN + col, rs);
                            curmol = mols[m][j];
                            rs = v;
                        } else {
                            rs += v;
                        }
                    }
                }
                if (curmol >= 0)
                    atomicAdd(dout + (size_t)curmol * HIDDEN + col, rs);
            }
        }
    }
}

// ================= tail kernels =================
// out[m][c] /= count(m)   (counts via binary search on sorted mol_idx)
__global__ void norm_kernel(float* __restrict__ out,
                            const int* __restrict__ mol_idx, int n_atoms)
{
    const int m = blockIdx.x;
    const int c = threadIdx.x;
    int l = 0, r = n_atoms;
    while (l < r) { const int mid = (l + r) >> 1; if (mol_idx[mid] < m) l = mid + 1; else r = mid; }
    const int start = l;
    r = n_atoms;
    while (l < r) { const int mid = (l + r) >> 1; if (mol_idx[mid] < m + 1) l = mid + 1; else r = mid; }
    out[(size_t)m * HIDDEN + c] /= fmaxf((float)(l - start), 1.0f);
}

__global__ __launch_bounds__(256) void fill_kernel(float* __restrict__ out, int n, float val)
{
    const int i = blockIdx.x * 256 + threadIdx.x;
    if (i < n) out[i] = val;
}

// ================= launch =================
extern "C" void kernel_launch(void* const* d_in, const int* in_sizes, int n_in,
                              void* d_out, int out_size, void* d_ws, size_t ws_size,
                              hipStream_t stream)
{
    const float* fatoms = (const float*)d_in[0];
    const float* fbonds = (const float*)d_in[1];
    const float* W_i    = (const float*)d_in[2];
    const float* W_h    = (const float*)d_in[3];
    const float* W_o    = (const float*)d_in[4];
    const float* b_o    = (const float*)d_in[5];
    const int*   agraph = (const int*)d_in[6];
    const int*   bgraph = (const int*)d_in[7];
    const int*   mol_idx= (const int*)d_in[8];

    const int n_atoms = in_sizes[0] / 38;          // 80000
    const int n_bonds = in_sizes[1] / 49;          // 160001
    const int n_mols  = out_size / HIDDEN;         // 4000

    const int Mb_b = (n_bonds + 63) & ~63;         // 160064
    const int Mb_a = (n_atoms + 63) & ~63;         // 80000

    const size_t eW  = (size_t)448 * 512;
    const size_t eFb = (size_t)Mb_b * 64;
    const size_t eFa = (size_t)Mb_a * 64;
    const size_t eX  = (size_t)Mb_b * 448;         // q8 bytes per buffer

    // bytes (~176 MB; ws = 256 MiB)
    const size_t need = 2 * eW * 2 + eFb * 2 + eFa * 2 +
                        2 * eX + 2 * (size_t)Mb_b * 4;

    const dim3 blk(256);

    if (ws_size >= need) {
        unsigned short* WhcatT  = (unsigned short*)d_ws;
        unsigned short* WocatT  = WhcatT + eW;
        unsigned short* fbondsP = WocatT + eW;
        unsigned short* fatomsP = fbondsP + eFb;
        unsigned char*  Xq0     = (unsigned char*)(fatomsP + eFa);
        unsigned char*  Xq1     = Xq0 + eX;
        float*          Xs0     = (float*)(Xq1 + eX);
        float*          Xs1     = Xs0 + Mb_b;

        // zero the accumulation target
        hipMemsetAsync(d_out, 0, (size_t)out_size * sizeof(float), stream);

        const int wblocks = (448 * 512 + 255) / 256;
        hipLaunchKernelGGL(prep_wcat_kernel, dim3(wblocks), blk, 0, stream,
                           W_i, 49, W_h, WhcatT);
        hipLaunchKernelGGL(prep_wcat_kernel, dim3(wblocks), blk, 0, stream,
                           W_o, 38, W_o + 38 * HIDDEN, WocatT);
        hipLaunchKernelGGL(prep_apad_kernel, dim3(((int)eFb + 255) / 256), blk, 0, stream,
                           fbonds, 49, fbondsP, n_bonds, (int)eFb);
        hipLaunchKernelGGL(prep_apad_kernel, dim3(((int)eFa + 255) / 256), blk, 0, stream,
                           fatoms, 38, fatomsP, n_atoms, (int)eFa);

        const dim3 gB(Mb_b / 64), gA(Mb_a / 64), tpb(512);

        unsigned char* Xq[2] = {Xq0, Xq1};
        float*         Xs[2] = {Xs0, Xs1};

        // X[0] = q8(relu(fbonds @ W_i))
        hipLaunchKernelGGL((gemm_mfma_kernel<0, 1>), gB, tpb, 0, stream,
                           fbondsP, (const unsigned char*)nullptr, (const float*)nullptr,
                           (const int*)nullptr, WhcatT, (const float*)nullptr,
                           Xq[0], Xs[0], (const int*)nullptr, (float*)nullptr,
                           n_bonds, 2);
        // 4 iterations, ping-pong: X[p^1] = q8(relu(fbonds@W_i + gather6(X[p])@W_h))
        int p = 0;
        for (int it = 0; it < 4; ++it) {
            hipLaunchKernelGGL((gemm_mfma_kernel<1, 1>), gB, tpb, 0, stream,
                               fbondsP, Xq[p], Xs[p], bgraph, WhcatT,
                               (const float*)nullptr,
                               Xq[p ^ 1], Xs[p ^ 1], (const int*)nullptr,
                               (float*)nullptr, n_bonds, 16);
            p ^= 1;
        }
        // atom readout fused with molecule-sum:
        // d_out += per-mol sums of relu([fatoms | gather6(X[p])] @ W_o + b_o)
        hipLaunchKernelGGL((gemm_mfma_kernel<1, 0>), gA, tpb, 0, stream,
                           fatomsP, Xq[p], Xs[p], agraph, WocatT, b_o,
                           (unsigned char*)nullptr, (float*)nullptr,
                           mol_idx, (float*)d_out, n_atoms, 16);
        // divide by per-molecule counts
        hipLaunchKernelGGL(norm_kernel, dim3(n_mols), dim3(HIDDEN), 0, stream,
                           (float*)d_out, mol_idx, n_atoms);
    } else {
        // diagnostic: absmax = 2272 + ws_MiB
        const float val = -(float)((double)ws_size / (1024.0 * 1024.0));
        hipLaunchKernelGGL(fill_kernel, dim3((out_size + 255) / 256), blk, 0, stream,
                           (float*)d_out, out_size, val);
    }
}